// Round 5
// baseline (1359.382 us; speedup 1.0000x reference)
//
#include <hip/hip_runtime.h>

#define EMB 64
#define SCAN_B 256
#define RPB 32      // rows per block (spmm)
#define RPW 8       // rows per wave  (spmm)
#define ECAP 1024   // staged edges per block (8KB LDS); Poisson(320) never exceeds this

// ---- clang vector typedefs for nontemporal builtins (HIP_vector_type invalid there) ----
typedef unsigned uint2v __attribute__((ext_vector_type(2)));
typedef float float4v __attribute__((ext_vector_type(4)));
typedef int int4v __attribute__((ext_vector_type(4)));

__device__ inline uint2 nt_load_u2(const uint2* p) {
    uint2v v = __builtin_nontemporal_load((const uint2v*)p);
    return make_uint2(v.x, v.y);
}
__device__ inline void nt_store_u2(uint2* p, uint2 v) {
    uint2v t; t.x = v.x; t.y = v.y;
    __builtin_nontemporal_store(t, (uint2v*)p);
}
__device__ inline float4 nt_load_f4(const float4* p) {
    float4v v = __builtin_nontemporal_load((const float4v*)p);
    return make_float4(v.x, v.y, v.z, v.w);
}
__device__ inline void nt_store_f4(float4* p, float4 v) {
    float4v t; t.x = v.x; t.y = v.y; t.z = v.z; t.w = v.w;
    __builtin_nontemporal_store(t, (float4v*)p);
}

// ---- bf16 helpers (manual, RNE) ----
__device__ inline unsigned short f2bf(float f) {
    unsigned u = __float_as_uint(f);
    return (unsigned short)((u + 0x7fffu + ((u >> 16) & 1u)) >> 16);
}
__device__ inline float bl(unsigned u) { return __uint_as_float(u << 16); }       // low bf16
__device__ inline float bh(unsigned u) { return __uint_as_float(u & 0xffff0000u); } // high bf16

// ---------------- CSR build ----------------

__global__ void zero_ints(int* __restrict__ p, int n) {
    int i = blockIdx.x * blockDim.x + threadIdx.x;
    if (i < n) p[i] = 0;
}

__global__ void hist_rows(const int* __restrict__ row, int* __restrict__ S, int E) {
    int e = blockIdx.x * blockDim.x + threadIdx.x;
    if (e < E) atomicAdd(&S[__builtin_nontemporal_load(row + e)], 1);
}

// vectorized histogram: 4 row-ids per thread, quarter the threads
__global__ void hist_rows4(const int* __restrict__ row, int* __restrict__ S, int E4) {
    int i = blockIdx.x * blockDim.x + threadIdx.x;
    if (i < E4) {
        int4v r = __builtin_nontemporal_load((const int4v*)row + i);
        atomicAdd(&S[r.x], 1);
        atomicAdd(&S[r.y], 1);
        atomicAdd(&S[r.z], 1);
        atomicAdd(&S[r.w], 1);
    }
}

__global__ void scan_block_sums(const int* __restrict__ S, int* __restrict__ bsum, int N) {
    __shared__ int sdata[SCAN_B];
    int i = blockIdx.x * SCAN_B + threadIdx.x;
    sdata[threadIdx.x] = (i < N) ? S[i] : 0;
    __syncthreads();
    for (int off = SCAN_B / 2; off > 0; off >>= 1) {
        if (threadIdx.x < off) sdata[threadIdx.x] += sdata[threadIdx.x + off];
        __syncthreads();
    }
    if (threadIdx.x == 0) bsum[blockIdx.x] = sdata[0];
}

__global__ void scan_sums(int* __restrict__ bsum, int nb) {
    __shared__ int part[1024];
    int t = threadIdx.x;
    int i0 = 2 * t, i1 = 2 * t + 1;
    int a = (i0 < nb) ? bsum[i0] : 0;
    int b = (i1 < nb) ? bsum[i1] : 0;
    part[t] = a + b;
    __syncthreads();
    for (int off = 1; off < 1024; off <<= 1) {
        int v = part[t];
        int add = (t >= off) ? part[t - off] : 0;
        __syncthreads();
        part[t] = v + add;
        __syncthreads();
    }
    int excl = (t == 0) ? 0 : part[t - 1];
    if (i0 < nb) bsum[i0] = excl;
    if (i1 < nb) bsum[i1] = excl + a;
}

__global__ void scan_apply(int* __restrict__ S, const int* __restrict__ bsum, int N) {
    __shared__ int sdata[SCAN_B];
    int i = blockIdx.x * SCAN_B + threadIdx.x;
    int v = (i < N) ? S[i] : 0;
    sdata[threadIdx.x] = v;
    __syncthreads();
    for (int off = 1; off < SCAN_B; off <<= 1) {
        int val = sdata[threadIdx.x];
        int add = (threadIdx.x >= off) ? sdata[threadIdx.x - off] : 0;
        __syncthreads();
        sdata[threadIdx.x] = val + add;
        __syncthreads();
    }
    int excl = (threadIdx.x == 0 ? 0 : sdata[threadIdx.x - 1]) + bsum[blockIdx.x];
    if (i < N) S[i] = excl;
}

// Single-pass scatter with NT stores. Round-4 evidence: the 8-pass ranged variant
// still showed 8.5x write amplification (274MB for 32MB payload) -- a row's ~80B
// of entries arrive spread over the whole kernel, so L2 line accumulation never
// happens regardless of XCD locality. So: stop paying 8x row re-reads for it,
// and stream the stores out nontemporally (32B-sector granularity at memory
// instead of 64B dirty-line evictions).
__global__ void scatter_edges(const int* __restrict__ row, const int* __restrict__ col,
                              const float* __restrict__ val,
                              int* __restrict__ S, uint2* __restrict__ epack, int E) {
    int e = blockIdx.x * blockDim.x + threadIdx.x;
    if (e >= E) return;
    int r = __builtin_nontemporal_load(row + e);
    int c = __builtin_nontemporal_load(col + e);
    float v = __builtin_nontemporal_load(val + e);
    int pos = atomicAdd(&S[r], 1);
    nt_store_u2(epack + pos, make_uint2((unsigned)c, __float_as_uint(v)));
}

// emb (fp32) -> bf16 copy for layer-1 gathers
__global__ void conv_bf16(const float4* __restrict__ src, uint2* __restrict__ dst, int n4) {
    int i = blockIdx.x * blockDim.x + threadIdx.x;
    if (i < n4) {
        float4 v = nt_load_f4(src + i);
        unsigned w0 = (unsigned)f2bf(v.x) | ((unsigned)f2bf(v.y) << 16);
        unsigned w1 = (unsigned)f2bf(v.z) | ((unsigned)f2bf(v.w) << 16);
        nt_store_u2(dst + i, make_uint2(w0, w1));
    }
}

// ---------------- SpMM v3: 32 rows/block, LDS-staged epack, 3-deep row pipeline ----
// Rows k+1 and k+2 have their epack entries + x-gathers in flight while row k is
// consumed (~12 gather lines in flight per wave). setprio(1) around the FMA consume:
// waves are independent (no barrier in main loop) so priority arbitration pays as in
// the attention case. VGPR pinned <=64 via launch_bounds so occupancy stays 32 w/CU.
template<bool STG>
__device__ __forceinline__ void spmm_rows(
    const uint2* __restrict__ epack, const uint2* __restrict__ esh, int beg0,
    const int* __restrict__ Ssh, int j0,
    const unsigned short* __restrict__ x, const float* __restrict__ emb,
    unsigned short* __restrict__ y, float* __restrict__ acc,
    int rb, int N, int mode, int lane, int grp, int d4)
{
    const uint2 z2 = make_uint2(0u, 0u);

#define EDG(i) (STG ? esh[(i) - beg0] : epack[i])
#define LOADR(J, B_, E_, P0, P1, P2, P3, G0, G1, G2, G3)                         \
    {                                                                            \
        B_ = Ssh[J]; E_ = Ssh[(J) + 1];                                          \
        int i0 = B_ + grp, i1 = i0 + 4, i2 = i0 + 8, i3 = i0 + 12;               \
        P0 = (i0 < E_) ? EDG(i0) : z2;                                           \
        P1 = (i1 < E_) ? EDG(i1) : z2;                                           \
        P2 = (i2 < E_) ? EDG(i2) : z2;                                           \
        P3 = (i3 < E_) ? EDG(i3) : z2;                                           \
        G0 = (i0 < E_) ? ((const uint2*)(x + ((size_t)P0.x << 6)))[d4] : z2;     \
        G1 = (i1 < E_) ? ((const uint2*)(x + ((size_t)P1.x << 6)))[d4] : z2;     \
        G2 = (i2 < E_) ? ((const uint2*)(x + ((size_t)P2.x << 6)))[d4] : z2;     \
        G3 = (i3 < E_) ? ((const uint2*)(x + ((size_t)P3.x << 6)))[d4] : z2;     \
    }

    int aB = 0, aE = 0;
    uint2 ap0 = z2, ap1 = z2, ap2 = z2, ap3 = z2, ag0 = z2, ag1 = z2, ag2 = z2, ag3 = z2;
    int bB = 0, bE = 0;
    uint2 bp0 = z2, bp1 = z2, bp2 = z2, bp3 = z2, bg0 = z2, bg1 = z2, bg2 = z2, bg3 = z2;
    int cB = 0, cE = 0;
    uint2 cp0 = z2, cp1 = z2, cp2 = z2, cp3 = z2, cg0 = z2, cg1 = z2, cg2 = z2, cg3 = z2;

    LOADR(j0,     aB, aE, ap0, ap1, ap2, ap3, ag0, ag1, ag2, ag3);
    LOADR(j0 + 1, bB, bE, bp0, bp1, bp2, bp3, bg0, bg1, bg2, bg3);

    for (int k = 0; k < RPW; ++k) {
        int j = j0 + k;
        int r = rb + j;
        if (k + 2 < RPW) {
            LOADR(j + 2, cB, cE, cp0, cp1, cp2, cp3, cg0, cg1, cg2, cg3);
        }

        float4 s = make_float4(0.f, 0.f, 0.f, 0.f);
        __builtin_amdgcn_s_setprio(1);
        {
            int i0 = aB + grp, i1 = i0 + 4, i2 = i0 + 8, i3 = i0 + 12;
            float w0 = (i0 < aE) ? __uint_as_float(ap0.y) : 0.f;
            float w1 = (i1 < aE) ? __uint_as_float(ap1.y) : 0.f;
            float w2 = (i2 < aE) ? __uint_as_float(ap2.y) : 0.f;
            float w3 = (i3 < aE) ? __uint_as_float(ap3.y) : 0.f;
            s.x += w0 * bl(ag0.x); s.y += w0 * bh(ag0.x); s.z += w0 * bl(ag0.y); s.w += w0 * bh(ag0.y);
            s.x += w1 * bl(ag1.x); s.y += w1 * bh(ag1.x); s.z += w1 * bl(ag1.y); s.w += w1 * bh(ag1.y);
            s.x += w2 * bl(ag2.x); s.y += w2 * bh(ag2.x); s.z += w2 * bl(ag2.y); s.w += w2 * bh(ag2.y);
            s.x += w3 * bl(ag3.x); s.y += w3 * bh(ag3.x); s.z += w3 * bl(ag3.y); s.w += w3 * bh(ag3.y);
        }
        __builtin_amdgcn_s_setprio(0);
        // rare tail: rows with deg > 16 (~3% at Poisson(10))
        for (int base = aB + 16; base < aE; base += 16) {
            int i0 = base + grp, i1 = i0 + 4, i2 = i0 + 8, i3 = i0 + 12;
            uint2 p0 = (i0 < aE) ? EDG(i0) : z2;
            uint2 p1 = (i1 < aE) ? EDG(i1) : z2;
            uint2 p2 = (i2 < aE) ? EDG(i2) : z2;
            uint2 p3 = (i3 < aE) ? EDG(i3) : z2;
            uint2 g0 = (i0 < aE) ? ((const uint2*)(x + ((size_t)p0.x << 6)))[d4] : z2;
            uint2 g1 = (i1 < aE) ? ((const uint2*)(x + ((size_t)p1.x << 6)))[d4] : z2;
            uint2 g2 = (i2 < aE) ? ((const uint2*)(x + ((size_t)p2.x << 6)))[d4] : z2;
            uint2 g3 = (i3 < aE) ? ((const uint2*)(x + ((size_t)p3.x << 6)))[d4] : z2;
            float w0 = (i0 < aE) ? __uint_as_float(p0.y) : 0.f;
            float w1 = (i1 < aE) ? __uint_as_float(p1.y) : 0.f;
            float w2 = (i2 < aE) ? __uint_as_float(p2.y) : 0.f;
            float w3 = (i3 < aE) ? __uint_as_float(p3.y) : 0.f;
            s.x += w0 * bl(g0.x); s.y += w0 * bh(g0.x); s.z += w0 * bl(g0.y); s.w += w0 * bh(g0.y);
            s.x += w1 * bl(g1.x); s.y += w1 * bh(g1.x); s.z += w1 * bl(g1.y); s.w += w1 * bh(g1.y);
            s.x += w2 * bl(g2.x); s.y += w2 * bh(g2.x); s.z += w2 * bl(g2.y); s.w += w2 * bh(g2.y);
            s.x += w3 * bl(g3.x); s.y += w3 * bh(g3.x); s.z += w3 * bl(g3.y); s.w += w3 * bh(g3.y);
        }

        s.x += __shfl_xor(s.x, 32); s.y += __shfl_xor(s.y, 32);
        s.z += __shfl_xor(s.z, 32); s.w += __shfl_xor(s.w, 32);
        s.x += __shfl_xor(s.x, 16); s.y += __shfl_xor(s.y, 16);
        s.z += __shfl_xor(s.z, 16); s.w += __shfl_xor(s.w, 16);

        if (lane < 16 && r < N) {
            size_t o4 = (size_t)r * 16 + d4;
            if (mode != 2) {
                unsigned w0 = (unsigned)f2bf(s.x) | ((unsigned)f2bf(s.y) << 16);
                unsigned w1 = (unsigned)f2bf(s.z) | ((unsigned)f2bf(s.w) << 16);
                nt_store_u2(((uint2*)y) + o4, make_uint2(w0, w1));
            }
            if (mode == 0) {
                float4 e4 = nt_load_f4(((const float4*)emb) + o4);
                nt_store_f4(((float4*)acc) + o4,
                            make_float4(e4.x + s.x, e4.y + s.y, e4.z + s.z, e4.w + s.w));
            } else if (mode == 1) {
                float4 a4 = nt_load_f4(((const float4*)acc) + o4);
                nt_store_f4(((float4*)acc) + o4,
                            make_float4(a4.x + s.x, a4.y + s.y, a4.z + s.z, a4.w + s.w));
            } else if (mode == 2) {
                float4 a4 = nt_load_f4(((const float4*)acc) + o4);
                nt_store_f4(((float4*)acc) + o4,
                            make_float4((a4.x + s.x) * 0.25f, (a4.y + s.y) * 0.25f,
                                        (a4.z + s.z) * 0.25f, (a4.w + s.w) * 0.25f));
            }
        }
        // rotate pipeline registers (a <- b <- c)
        aB = bB; aE = bE;
        ap0 = bp0; ap1 = bp1; ap2 = bp2; ap3 = bp3;
        ag0 = bg0; ag1 = bg1; ag2 = bg2; ag3 = bg3;
        bB = cB; bE = cE;
        bp0 = cp0; bp1 = cp1; bp2 = cp2; bp3 = cp3;
        bg0 = cg0; bg1 = cg1; bg2 = cg2; bg3 = cg3;
    }
#undef LOADR
#undef EDG
}

__global__ __launch_bounds__(256, 8) void spmm_csr2(
    const uint2* __restrict__ epack, const int* __restrict__ S,
    const unsigned short* __restrict__ x, const float* __restrict__ emb,
    unsigned short* __restrict__ y, float* __restrict__ acc,
    int N, int mode)
{
    __shared__ int Ssh[RPB + 1];
    __shared__ uint2 esh[ECAP];

    int tid = threadIdx.x;
    int rb = blockIdx.x * RPB;

    if (tid <= RPB) {
        int rr = rb - 1 + tid;
        Ssh[tid] = (rr < 0) ? 0 : S[rr < N ? rr : (N - 1)];
    }
    __syncthreads();

    int beg0 = Ssh[0];
    int nE = Ssh[RPB] - beg0;
    bool staged = (nE <= ECAP);
    if (staged) {
        for (int i = tid; i < nE; i += 256) esh[i] = nt_load_u2(epack + beg0 + i);
    }
    __syncthreads();

    int wid = tid >> 6, lane = tid & 63;
    int grp = lane >> 4, d4 = lane & 15;
    int j0 = wid * RPW;

    if (staged)
        spmm_rows<true >(epack, esh, beg0, Ssh, j0, x, emb, y, acc, rb, N, mode, lane, grp, d4);
    else
        spmm_rows<false>(epack, esh, beg0, Ssh, j0, x, emb, y, acc, rb, N, mode, lane, grp, d4);
}

// ---------------- fallback path (round-1 atomic version, fp32) ----------------

__global__ void lgcn_init(const float4* __restrict__ emb, float4* __restrict__ A,
                          float4* __restrict__ acc, float4* __restrict__ B, int n4) {
    int i = blockIdx.x * blockDim.x + threadIdx.x;
    if (i < n4) { float4 v = emb[i]; A[i] = v; acc[i] = v; B[i] = make_float4(0,0,0,0); }
}
__global__ void lgcn_spmm(const int* __restrict__ row, const int* __restrict__ col,
                          const float* __restrict__ val, const float* __restrict__ x,
                          float* __restrict__ y, int E) {
    int gid = blockIdx.x * blockDim.x + threadIdx.x;
    int e = gid >> 6;
    if (e >= E) return;
    int d = threadIdx.x & 63;
    atomicAdd(y + (size_t)row[e] * EMB + d, val[e] * x[(size_t)col[e] * EMB + d]);
}
__global__ void lgcn_addzero(float4* __restrict__ acc, const float4* __restrict__ X,
                             float4* __restrict__ Y, int n4) {
    int i = blockIdx.x * blockDim.x + threadIdx.x;
    if (i < n4) {
        float4 a = acc[i]; float4 xv = X[i];
        a.x += xv.x; a.y += xv.y; a.z += xv.z; a.w += xv.w;
        acc[i] = a; Y[i] = make_float4(0,0,0,0);
    }
}
__global__ void lgcn_final(float4* __restrict__ acc, const float4* __restrict__ X, int n4) {
    int i = blockIdx.x * blockDim.x + threadIdx.x;
    if (i < n4) {
        float4 a = acc[i]; float4 xv = X[i];
        a.x = (a.x + xv.x) * 0.25f; a.y = (a.y + xv.y) * 0.25f;
        a.z = (a.z + xv.z) * 0.25f; a.w = (a.w + xv.w) * 0.25f;
        acc[i] = a;
    }
}

extern "C" void kernel_launch(void* const* d_in, const int* in_sizes, int n_in,
                              void* d_out, int out_size, void* d_ws, size_t ws_size,
                              hipStream_t stream) {
    const float* emb = (const float*)d_in[0];
    const int*   row = (const int*)d_in[1];
    const int*   col = (const int*)d_in[2];
    const float* val = (const float*)d_in[3];
    float* acc = (float*)d_out;

    const int N = in_sizes[0] / EMB;   // 400000
    const int E = in_sizes[1];         // 4000000
    const int TB = 256;

    const size_t buf_elems = (size_t)N * EMB;
    const int nb = (N + SCAN_B - 1) / SCAN_B;

    // CSR ws layout: epack[E] | X0b | X1b | X2b (bf16) | S[N] | bsum[nb]
    const size_t need = (size_t)E * 8 + buf_elems * 2 * 3 + (size_t)N * 4 + (size_t)nb * 4;

    if (ws_size >= need) {
        uint2* epack = (uint2*)d_ws;
        unsigned short* X0 = (unsigned short*)(epack + E);
        unsigned short* X1 = X0 + buf_elems;
        unsigned short* X2 = X1 + buf_elems;
        int* S    = (int*)(X2 + buf_elems);
        int* bsum = S + N;

        const int eb  = (E + TB - 1) / TB;
        const int nbN = (N + TB - 1) / TB;
        const int n4  = (int)(buf_elems / 4);
        const int cvb = (n4 + TB - 1) / TB;
        const int spmm_blocks = (N + RPB - 1) / RPB;

        // build CSR (reused by all 3 layers)
        zero_ints<<<nbN, TB, 0, stream>>>(S, N);
        if ((E & 3) == 0) {
            const int e4b = (E / 4 + TB - 1) / TB;
            hist_rows4<<<e4b, TB, 0, stream>>>(row, S, E / 4);
        } else {
            hist_rows<<<eb, TB, 0, stream>>>(row, S, E);
        }
        scan_block_sums<<<nb, SCAN_B, 0, stream>>>(S, bsum, N);
        scan_sums<<<1, 1024, 0, stream>>>(bsum, nb);
        scan_apply<<<nb, SCAN_B, 0, stream>>>(S, bsum, N);
        scatter_edges<<<eb, TB, 0, stream>>>(row, col, val, S, epack, E);
        conv_bf16<<<cvb, TB, 0, stream>>>((const float4*)emb, (uint2*)X0, n4);

        // 3 fused SpMM layers (bf16 gathers, fp32 accumulate/acc)
        spmm_csr2<<<spmm_blocks, TB, 0, stream>>>(epack, S, X0, emb, X1, acc, N, 0);
        spmm_csr2<<<spmm_blocks, TB, 0, stream>>>(epack, S, X1, nullptr, X2, acc, N, 1);
        spmm_csr2<<<spmm_blocks, TB, 0, stream>>>(epack, S, X2, nullptr, nullptr, acc, N, 2);
    } else {
        float* A = (float*)d_ws;
        float* B = A + buf_elems;
        const int n4 = (int)(buf_elems / 4);
        const int ew_blocks = (n4 + TB - 1) / TB;
        const int spmm_blocks = (E + 3) / 4;
        lgcn_init<<<ew_blocks, TB, 0, stream>>>((const float4*)emb, (float4*)A,
                                                (float4*)acc, (float4*)B, n4);
        lgcn_spmm<<<spmm_blocks, TB, 0, stream>>>(row, col, val, A, B, E);
        lgcn_addzero<<<ew_blocks, TB, 0, stream>>>((float4*)acc, (const float4*)B,
                                                   (float4*)A, n4);
        lgcn_spmm<<<spmm_blocks, TB, 0, stream>>>(row, col, val, B, A, E);
        lgcn_addzero<<<ew_blocks, TB, 0, stream>>>((float4*)acc, (const float4*)A,
                                                   (float4*)B, n4);
        lgcn_spmm<<<spmm_blocks, TB, 0, stream>>>(row, col, val, A, B, E);
        lgcn_final<<<ew_blocks, TB, 0, stream>>>((float4*)acc, (const float4*)B, n4);
    }
}

// Round 6
// 980.962 us; speedup vs baseline: 1.3858x; 1.3858x over previous
//
#include <hip/hip_runtime.h>

#define EMB 64
#define SCAN_B 256
#define RPB 32      // rows per block (spmm)
#define RPW 8       // rows per wave  (spmm)
#define ECAP 1024   // staged edges per block (8KB LDS); Poisson(320) never exceeds this

// ---- clang vector typedefs for nontemporal builtins (HIP_vector_type invalid there) ----
typedef unsigned uint2v __attribute__((ext_vector_type(2)));
typedef float float4v __attribute__((ext_vector_type(4)));
typedef int int4v __attribute__((ext_vector_type(4)));

__device__ inline uint2 nt_load_u2(const uint2* p) {
    uint2v v = __builtin_nontemporal_load((const uint2v*)p);
    return make_uint2(v.x, v.y);
}
__device__ inline void nt_store_u2(uint2* p, uint2 v) {
    uint2v t; t.x = v.x; t.y = v.y;
    __builtin_nontemporal_store(t, (uint2v*)p);
}
__device__ inline float4 nt_load_f4(const float4* p) {
    float4v v = __builtin_nontemporal_load((const float4v*)p);
    return make_float4(v.x, v.y, v.z, v.w);
}
__device__ inline void nt_store_f4(float4* p, float4 v) {
    float4v t; t.x = v.x; t.y = v.y; t.z = v.z; t.w = v.w;
    __builtin_nontemporal_store(t, (float4v*)p);
}

// ---- bf16 helpers (manual, RNE) ----
__device__ inline unsigned short f2bf(float f) {
    unsigned u = __float_as_uint(f);
    return (unsigned short)((u + 0x7fffu + ((u >> 16) & 1u)) >> 16);
}
__device__ inline float bl(unsigned u) { return __uint_as_float(u << 16); }       // low bf16
__device__ inline float bh(unsigned u) { return __uint_as_float(u & 0xffff0000u); } // high bf16

// ---------------- CSR build ----------------

__global__ void zero_ints(int* __restrict__ p, int n) {
    int i = blockIdx.x * blockDim.x + threadIdx.x;
    if (i < n) p[i] = 0;
}

__global__ void hist_rows(const int* __restrict__ row, int* __restrict__ S, int E) {
    int e = blockIdx.x * blockDim.x + threadIdx.x;
    if (e < E) atomicAdd(&S[__builtin_nontemporal_load(row + e)], 1);
}

// vectorized histogram: 4 row-ids per thread, quarter the threads
__global__ void hist_rows4(const int* __restrict__ row, int* __restrict__ S, int E4) {
    int i = blockIdx.x * blockDim.x + threadIdx.x;
    if (i < E4) {
        int4v r = __builtin_nontemporal_load((const int4v*)row + i);
        atomicAdd(&S[r.x], 1);
        atomicAdd(&S[r.y], 1);
        atomicAdd(&S[r.z], 1);
        atomicAdd(&S[r.w], 1);
    }
}

__global__ void scan_block_sums(const int* __restrict__ S, int* __restrict__ bsum, int N) {
    __shared__ int sdata[SCAN_B];
    int i = blockIdx.x * SCAN_B + threadIdx.x;
    sdata[threadIdx.x] = (i < N) ? S[i] : 0;
    __syncthreads();
    for (int off = SCAN_B / 2; off > 0; off >>= 1) {
        if (threadIdx.x < off) sdata[threadIdx.x] += sdata[threadIdx.x + off];
        __syncthreads();
    }
    if (threadIdx.x == 0) bsum[blockIdx.x] = sdata[0];
}

__global__ void scan_sums(int* __restrict__ bsum, int nb) {
    __shared__ int part[1024];
    int t = threadIdx.x;
    int i0 = 2 * t, i1 = 2 * t + 1;
    int a = (i0 < nb) ? bsum[i0] : 0;
    int b = (i1 < nb) ? bsum[i1] : 0;
    part[t] = a + b;
    __syncthreads();
    for (int off = 1; off < 1024; off <<= 1) {
        int v = part[t];
        int add = (t >= off) ? part[t - off] : 0;
        __syncthreads();
        part[t] = v + add;
        __syncthreads();
    }
    int excl = (t == 0) ? 0 : part[t - 1];
    if (i0 < nb) bsum[i0] = excl;
    if (i1 < nb) bsum[i1] = excl + a;
}

__global__ void scan_apply(int* __restrict__ S, const int* __restrict__ bsum, int N) {
    __shared__ int sdata[SCAN_B];
    int i = blockIdx.x * SCAN_B + threadIdx.x;
    int v = (i < N) ? S[i] : 0;
    sdata[threadIdx.x] = v;
    __syncthreads();
    for (int off = 1; off < SCAN_B; off <<= 1) {
        int val = sdata[threadIdx.x];
        int add = (threadIdx.x >= off) ? sdata[threadIdx.x - off] : 0;
        __syncthreads();
        sdata[threadIdx.x] = val + add;
        __syncthreads();
    }
    int excl = (threadIdx.x == 0 ? 0 : sdata[threadIdx.x - 1]) + bsum[blockIdx.x];
    if (i < N) S[i] = excl;
}

// Ranged scatter (round-4 config, reverted from NT-store experiment: NT stores of
// scattered 8B payloads ran at 0.8 TB/s -- each became a lone partial-sector DRAM
// transaction. Ranged+temporal streams 274MB through L2 at 2.5 TB/s = 190us).
__global__ void scatter_edges_ranged(const int* __restrict__ row, const int* __restrict__ col,
                                     const float* __restrict__ val,
                                     int* __restrict__ S, uint2* __restrict__ epack,
                                     int E, int rstep) {
    int pass  = blockIdx.x & 7;
    int chunk = blockIdx.x >> 3;
    int e = chunk * blockDim.x + threadIdx.x;
    if (e >= E) return;
    int r = __builtin_nontemporal_load(row + e);
    int lo = pass * rstep;
    if (r < lo || r >= lo + rstep) return;
    int c = __builtin_nontemporal_load(col + e);
    float v = __builtin_nontemporal_load(val + e);
    int pos = atomicAdd(&S[r], 1);
    epack[pos] = make_uint2((unsigned)c, __float_as_uint(v));  // temporal: combine in L2
}

// emb (fp32) -> bf16 copy for layer-1 gathers
__global__ void conv_bf16(const float4* __restrict__ src, uint2* __restrict__ dst, int n4) {
    int i = blockIdx.x * blockDim.x + threadIdx.x;
    if (i < n4) {
        float4 v = nt_load_f4(src + i);
        unsigned w0 = (unsigned)f2bf(v.x) | ((unsigned)f2bf(v.y) << 16);
        unsigned w1 = (unsigned)f2bf(v.z) | ((unsigned)f2bf(v.w) << 16);
        nt_store_u2(dst + i, make_uint2(w0, w1));
    }
}

// ---------------- SpMM v4: round-4 structure (2-deep pipeline, VGPR=32) ----------------
// Traffic restructure: acc = emb + s1 + s2 + s3, and X1=bf16(s1), X2=bf16(s2) are
// already materialized for the next layer's gathers. So layers 1-2 write ONLY y
// (no acc RMW: saves 204MB/layer), and layer 3 computes
//   acc = 0.25*(emb + up(X1) + up(X2) + s3)
// reading emb/X1/X2 contiguously. Numerics: substitutes bf16(s1) for fp32 s1 in the
// sum -> added rounding ~2^-9*|s1| ~ 3e-6, negligible vs the 4.9e-4 absmax budget.
// mode 0/1: y = bf16(s) only | mode 2: final acc (y unused)
template<bool STG>
__device__ __forceinline__ void spmm_rows(
    const uint2* __restrict__ epack, const uint2* __restrict__ esh, int beg0,
    const int* __restrict__ Ssh, int j0,
    const unsigned short* __restrict__ x, const float* __restrict__ emb,
    const uint2* __restrict__ x1b, const uint2* __restrict__ x2b,
    unsigned short* __restrict__ y, float* __restrict__ acc,
    int rb, int N, int mode, int lane, int grp, int d4)
{
    const uint2 z2 = make_uint2(0u, 0u);

#define EDG(i) (STG ? esh[(i) - beg0] : epack[i])
#define LOADR(J, B_, E_, P0, P1, P2, P3, G0, G1, G2, G3)                         \
    {                                                                            \
        B_ = Ssh[J]; E_ = Ssh[(J) + 1];                                          \
        int i0 = B_ + grp, i1 = i0 + 4, i2 = i0 + 8, i3 = i0 + 12;               \
        P0 = (i0 < E_) ? EDG(i0) : z2;                                           \
        P1 = (i1 < E_) ? EDG(i1) : z2;                                           \
        P2 = (i2 < E_) ? EDG(i2) : z2;                                           \
        P3 = (i3 < E_) ? EDG(i3) : z2;                                           \
        G0 = (i0 < E_) ? ((const uint2*)(x + ((size_t)P0.x << 6)))[d4] : z2;     \
        G1 = (i1 < E_) ? ((const uint2*)(x + ((size_t)P1.x << 6)))[d4] : z2;     \
        G2 = (i2 < E_) ? ((const uint2*)(x + ((size_t)P2.x << 6)))[d4] : z2;     \
        G3 = (i3 < E_) ? ((const uint2*)(x + ((size_t)P3.x << 6)))[d4] : z2;     \
    }

    int aB = 0, aE = 0;
    uint2 ap0 = z2, ap1 = z2, ap2 = z2, ap3 = z2, ag0 = z2, ag1 = z2, ag2 = z2, ag3 = z2;
    int bB = 0, bE = 0;
    uint2 bp0 = z2, bp1 = z2, bp2 = z2, bp3 = z2, bg0 = z2, bg1 = z2, bg2 = z2, bg3 = z2;

    LOADR(j0, aB, aE, ap0, ap1, ap2, ap3, ag0, ag1, ag2, ag3);

    for (int k = 0; k < RPW; ++k) {
        int j = j0 + k;
        int r = rb + j;
        if (k + 1 < RPW) {
            LOADR(j + 1, bB, bE, bp0, bp1, bp2, bp3, bg0, bg1, bg2, bg3);
        }

        float4 s = make_float4(0.f, 0.f, 0.f, 0.f);
        {
            int i0 = aB + grp, i1 = i0 + 4, i2 = i0 + 8, i3 = i0 + 12;
            float w0 = (i0 < aE) ? __uint_as_float(ap0.y) : 0.f;
            float w1 = (i1 < aE) ? __uint_as_float(ap1.y) : 0.f;
            float w2 = (i2 < aE) ? __uint_as_float(ap2.y) : 0.f;
            float w3 = (i3 < aE) ? __uint_as_float(ap3.y) : 0.f;
            s.x += w0 * bl(ag0.x); s.y += w0 * bh(ag0.x); s.z += w0 * bl(ag0.y); s.w += w0 * bh(ag0.y);
            s.x += w1 * bl(ag1.x); s.y += w1 * bh(ag1.x); s.z += w1 * bl(ag1.y); s.w += w1 * bh(ag1.y);
            s.x += w2 * bl(ag2.x); s.y += w2 * bh(ag2.x); s.z += w2 * bl(ag2.y); s.w += w2 * bh(ag2.y);
            s.x += w3 * bl(ag3.x); s.y += w3 * bh(ag3.x); s.z += w3 * bl(ag3.y); s.w += w3 * bh(ag3.y);
        }
        // rare tail: rows with deg > 16 (~3% at Poisson(10))
        for (int base = aB + 16; base < aE; base += 16) {
            int i0 = base + grp, i1 = i0 + 4, i2 = i0 + 8, i3 = i0 + 12;
            uint2 p0 = (i0 < aE) ? EDG(i0) : z2;
            uint2 p1 = (i1 < aE) ? EDG(i1) : z2;
            uint2 p2 = (i2 < aE) ? EDG(i2) : z2;
            uint2 p3 = (i3 < aE) ? EDG(i3) : z2;
            uint2 g0 = (i0 < aE) ? ((const uint2*)(x + ((size_t)p0.x << 6)))[d4] : z2;
            uint2 g1 = (i1 < aE) ? ((const uint2*)(x + ((size_t)p1.x << 6)))[d4] : z2;
            uint2 g2 = (i2 < aE) ? ((const uint2*)(x + ((size_t)p2.x << 6)))[d4] : z2;
            uint2 g3 = (i3 < aE) ? ((const uint2*)(x + ((size_t)p3.x << 6)))[d4] : z2;
            float w0 = (i0 < aE) ? __uint_as_float(p0.y) : 0.f;
            float w1 = (i1 < aE) ? __uint_as_float(p1.y) : 0.f;
            float w2 = (i2 < aE) ? __uint_as_float(p2.y) : 0.f;
            float w3 = (i3 < aE) ? __uint_as_float(p3.y) : 0.f;
            s.x += w0 * bl(g0.x); s.y += w0 * bh(g0.x); s.z += w0 * bl(g0.y); s.w += w0 * bh(g0.y);
            s.x += w1 * bl(g1.x); s.y += w1 * bh(g1.x); s.z += w1 * bl(g1.y); s.w += w1 * bh(g1.y);
            s.x += w2 * bl(g2.x); s.y += w2 * bh(g2.x); s.z += w2 * bl(g2.y); s.w += w2 * bh(g2.y);
            s.x += w3 * bl(g3.x); s.y += w3 * bh(g3.x); s.z += w3 * bl(g3.y); s.w += w3 * bh(g3.y);
        }

        s.x += __shfl_xor(s.x, 32); s.y += __shfl_xor(s.y, 32);
        s.z += __shfl_xor(s.z, 32); s.w += __shfl_xor(s.w, 32);
        s.x += __shfl_xor(s.x, 16); s.y += __shfl_xor(s.y, 16);
        s.z += __shfl_xor(s.z, 16); s.w += __shfl_xor(s.w, 16);

        if (lane < 16 && r < N) {
            size_t o4 = (size_t)r * 16 + d4;
            if (mode != 2) {
                // y (bf16, 8B/lane coalesced)
                unsigned w0 = (unsigned)f2bf(s.x) | ((unsigned)f2bf(s.y) << 16);
                unsigned w1 = (unsigned)f2bf(s.z) | ((unsigned)f2bf(s.w) << 16);
                nt_store_u2(((uint2*)y) + o4, make_uint2(w0, w1));
            } else {
                float4 e4 = nt_load_f4(((const float4*)emb) + o4);
                uint2 a1 = nt_load_u2(x1b + o4);
                uint2 a2 = nt_load_u2(x2b + o4);
                float rx = e4.x + bl(a1.x) + bl(a2.x) + s.x;
                float ry = e4.y + bh(a1.x) + bh(a2.x) + s.y;
                float rz = e4.z + bl(a1.y) + bl(a2.y) + s.z;
                float rw = e4.w + bh(a1.y) + bh(a2.y) + s.w;
                nt_store_f4(((float4*)acc) + o4,
                            make_float4(rx * 0.25f, ry * 0.25f, rz * 0.25f, rw * 0.25f));
            }
        }
        // rotate pipeline registers
        aB = bB; aE = bE;
        ap0 = bp0; ap1 = bp1; ap2 = bp2; ap3 = bp3;
        ag0 = bg0; ag1 = bg1; ag2 = bg2; ag3 = bg3;
    }
#undef LOADR
#undef EDG
}

__global__ __launch_bounds__(256) void spmm_csr2(
    const uint2* __restrict__ epack, const int* __restrict__ S,
    const unsigned short* __restrict__ x, const float* __restrict__ emb,
    const uint2* __restrict__ x1b, const uint2* __restrict__ x2b,
    unsigned short* __restrict__ y, float* __restrict__ acc,
    int N, int mode)
{
    __shared__ int Ssh[RPB + 1];
    __shared__ uint2 esh[ECAP];

    int tid = threadIdx.x;
    int rb = blockIdx.x * RPB;

    if (tid <= RPB) {
        int rr = rb - 1 + tid;
        Ssh[tid] = (rr < 0) ? 0 : S[rr < N ? rr : (N - 1)];
    }
    __syncthreads();

    int beg0 = Ssh[0];
    int nE = Ssh[RPB] - beg0;
    bool staged = (nE <= ECAP);
    if (staged) {
        for (int i = tid; i < nE; i += 256) esh[i] = nt_load_u2(epack + beg0 + i);
    }
    __syncthreads();

    int wid = tid >> 6, lane = tid & 63;
    int grp = lane >> 4, d4 = lane & 15;
    int j0 = wid * RPW;

    if (staged)
        spmm_rows<true >(epack, esh, beg0, Ssh, j0, x, emb, x1b, x2b, y, acc, rb, N, mode, lane, grp, d4);
    else
        spmm_rows<false>(epack, esh, beg0, Ssh, j0, x, emb, x1b, x2b, y, acc, rb, N, mode, lane, grp, d4);
}

// ---------------- fallback path (round-1 atomic version, fp32) ----------------

__global__ void lgcn_init(const float4* __restrict__ emb, float4* __restrict__ A,
                          float4* __restrict__ acc, float4* __restrict__ B, int n4) {
    int i = blockIdx.x * blockDim.x + threadIdx.x;
    if (i < n4) { float4 v = emb[i]; A[i] = v; acc[i] = v; B[i] = make_float4(0,0,0,0); }
}
__global__ void lgcn_spmm(const int* __restrict__ row, const int* __restrict__ col,
                          const float* __restrict__ val, const float* __restrict__ x,
                          float* __restrict__ y, int E) {
    int gid = blockIdx.x * blockDim.x + threadIdx.x;
    int e = gid >> 6;
    if (e >= E) return;
    int d = threadIdx.x & 63;
    atomicAdd(y + (size_t)row[e] * EMB + d, val[e] * x[(size_t)col[e] * EMB + d]);
}
__global__ void lgcn_addzero(float4* __restrict__ acc, const float4* __restrict__ X,
                             float4* __restrict__ Y, int n4) {
    int i = blockIdx.x * blockDim.x + threadIdx.x;
    if (i < n4) {
        float4 a = acc[i]; float4 xv = X[i];
        a.x += xv.x; a.y += xv.y; a.z += xv.z; a.w += xv.w;
        acc[i] = a; Y[i] = make_float4(0,0,0,0);
    }
}
__global__ void lgcn_final(float4* __restrict__ acc, const float4* __restrict__ X, int n4) {
    int i = blockIdx.x * blockDim.x + threadIdx.x;
    if (i < n4) {
        float4 a = acc[i]; float4 xv = X[i];
        a.x = (a.x + xv.x) * 0.25f; a.y = (a.y + xv.y) * 0.25f;
        a.z = (a.z + xv.z) * 0.25f; a.w = (a.w + xv.w) * 0.25f;
        acc[i] = a;
    }
}

extern "C" void kernel_launch(void* const* d_in, const int* in_sizes, int n_in,
                              void* d_out, int out_size, void* d_ws, size_t ws_size,
                              hipStream_t stream) {
    const float* emb = (const float*)d_in[0];
    const int*   row = (const int*)d_in[1];
    const int*   col = (const int*)d_in[2];
    const float* val = (const float*)d_in[3];
    float* acc = (float*)d_out;

    const int N = in_sizes[0] / EMB;   // 400000
    const int E = in_sizes[1];         // 4000000
    const int TB = 256;

    const size_t buf_elems = (size_t)N * EMB;
    const int nb = (N + SCAN_B - 1) / SCAN_B;

    // CSR ws layout: epack[E] | X0b | X1b | X2b (bf16) | S[N] | bsum[nb]
    const size_t need = (size_t)E * 8 + buf_elems * 2 * 3 + (size_t)N * 4 + (size_t)nb * 4;

    if (ws_size >= need) {
        uint2* epack = (uint2*)d_ws;
        unsigned short* X0 = (unsigned short*)(epack + E);
        unsigned short* X1 = X0 + buf_elems;
        unsigned short* X2 = X1 + buf_elems;
        int* S    = (int*)(X2 + buf_elems);
        int* bsum = S + N;

        const int eb  = (E + TB - 1) / TB;
        const int nbN = (N + TB - 1) / TB;
        const int n4  = (int)(buf_elems / 4);
        const int cvb = (n4 + TB - 1) / TB;
        const int spmm_blocks = (N + RPB - 1) / RPB;
        const int rstep = (N + 7) / 8;

        // build CSR (reused by all 3 layers)
        zero_ints<<<nbN, TB, 0, stream>>>(S, N);
        if ((E & 3) == 0) {
            const int e4b = (E / 4 + TB - 1) / TB;
            hist_rows4<<<e4b, TB, 0, stream>>>(row, S, E / 4);
        } else {
            hist_rows<<<eb, TB, 0, stream>>>(row, S, E);
        }
        scan_block_sums<<<nb, SCAN_B, 0, stream>>>(S, bsum, N);
        scan_sums<<<1, 1024, 0, stream>>>(bsum, nb);
        scan_apply<<<nb, SCAN_B, 0, stream>>>(S, bsum, N);
        scatter_edges_ranged<<<eb * 8, TB, 0, stream>>>(row, col, val, S, epack, E, rstep);
        conv_bf16<<<cvb, TB, 0, stream>>>((const float4*)emb, (uint2*)X0, n4);

        // layers 1-2: y only; layer 3: acc = 0.25*(emb + X1 + X2 + s3)
        spmm_csr2<<<spmm_blocks, TB, 0, stream>>>(epack, S, X0, nullptr, nullptr, nullptr,
                                                  X1, nullptr, N, 0);
        spmm_csr2<<<spmm_blocks, TB, 0, stream>>>(epack, S, X1, nullptr, nullptr, nullptr,
                                                  X2, nullptr, N, 1);
        spmm_csr2<<<spmm_blocks, TB, 0, stream>>>(epack, S, X2, emb,
                                                  (const uint2*)X1, (const uint2*)X2,
                                                  nullptr, acc, N, 2);
    } else {
        float* A = (float*)d_ws;
        float* B = A + buf_elems;
        const int n4 = (int)(buf_elems / 4);
        const int ew_blocks = (n4 + TB - 1) / TB;
        const int spmm_blocks = (E + 3) / 4;
        lgcn_init<<<ew_blocks, TB, 0, stream>>>((const float4*)emb, (float4*)A,
                                                (float4*)acc, (float4*)B, n4);
        lgcn_spmm<<<spmm_blocks, TB, 0, stream>>>(row, col, val, A, B, E);
        lgcn_addzero<<<ew_blocks, TB, 0, stream>>>((float4*)acc, (const float4*)B,
                                                   (float4*)A, n4);
        lgcn_spmm<<<spmm_blocks, TB, 0, stream>>>(row, col, val, B, A, E);
        lgcn_addzero<<<ew_blocks, TB, 0, stream>>>((float4*)acc, (const float4*)A,
                                                   (float4*)B, n4);
        lgcn_spmm<<<spmm_blocks, TB, 0, stream>>>(row, col, val, A, B, E);
        lgcn_final<<<ew_blocks, TB, 0, stream>>>((float4*)acc, (const float4*)B, n4);
    }
}